// Round 6
// baseline (1098.741 us; speedup 1.0000x reference)
//
#include <hip/hip_runtime.h>
#include <hip/hip_cooperative_groups.h>
#include <math.h>

namespace cg = cooperative_groups;

#define VOCAB 32000
#define DIM 1024
#define BB 2
#define SS 512
#define BS (BB*SS)
#define MASK_ID 31999
#define EXPAND_ID 31998
#define NSTEPS 4
#define TOPK 50
#define NR 8
#define NEGF (-3.4028234663852886e38f)

#define NDC_H 64            // h split-K chunks (DH=16 each)
#define NDCL 32             // logits split-K chunks (DL=32 each)
#define NCH 500             // 64-wide value chunks per row
#define CAP 256

// -------- persistent device state (re-initialized every launch) ------------
__device__ int      g_x[BS];
__device__ int      g_x0[BS];
__device__ int      g_tok_used[BS];
__device__ float    g_conf[BS];
__device__ int      g_row_tok[NR];
__device__ float    g_row_conf[NR];
__device__ int      g_row_x0[NR];
__device__ float    g_h_part[NDC_H][NR][DIM];
__device__ float    g_h[NR][DIM];
__device__ float    g_lpart[NDCL][NR][VOCAB];
__device__ float    g_logits[NR][VOCAB];
__device__ float    g_step_conf[NSTEPS];
__device__ unsigned g_hist16[NR][65536];
__device__ float    g_cmax[NR][512];
__device__ int      g_camax[NR][512];
__device__ float    g_cz[NR][512];
__device__ unsigned g_thr[NR];
__device__ float    g_mx_r[NR];
__device__ float    g_Z_r[NR];
__device__ int      g_amax_r[NR];
__device__ int      g_cand_cnt[NR];
__device__ float    g_cand[NR][CAP];

__device__ inline unsigned keyf(float f) {
    unsigned b = __float_as_uint(f);
    return b ^ ((b & 0x80000000u) ? 0xFFFFFFFFu : 0x80000000u);
}

// logits accumulate, row-count specialized (all register indices static)
template<int NA>
__device__ __forceinline__ void accumL(const float* __restrict__ Wout,
                                       const float (*sh)[32], int dc, int c) {
    float4 acc[NA];
    #pragma unroll
    for (int r = 0; r < NA; r++) acc[r] = make_float4(0.f, 0.f, 0.f, 0.f);
    const float* W = Wout + (size_t)dc * 32 * VOCAB + c;
    #pragma unroll 4
    for (int dd = 0; dd < 32; dd++) {
        float4 w = *(const float4*)(W + (size_t)dd * VOCAB);
        #pragma unroll
        for (int r = 0; r < NA; r++) {
            float s = sh[r][dd];
            acc[r].x += s * w.x; acc[r].y += s * w.y;
            acc[r].z += s * w.z; acc[r].w += s * w.w;
        }
    }
    #pragma unroll
    for (int r = 0; r < NA; r++)
        *(float4*)&g_lpart[dc][r][c] = acc[r];
}

__global__ __launch_bounds__(1024)
void k_mega(const int* __restrict__ xin, const float* __restrict__ emb,
            const float* __restrict__ W1, const float* __restrict__ Wout,
            float* __restrict__ out) {
    cg::grid_group grid = cg::this_grid();
    const int bid = blockIdx.x;
    const int tid = threadIdx.x;

    __shared__ float    se[NR][16];
    __shared__ float    sh[NR][32];
    __shared__ float    red_f[1024];
    __shared__ int      red_i[1024];
    __shared__ unsigned su_[1024];
    __shared__ unsigned sup[32];
    __shared__ float    candL[NR][CAP];
    __shared__ float    sorted_[NR][TOPK];
    __shared__ int      s_tok[NR];
    __shared__ int      s_nact;

    // ---- init + step-0 requests (block 0) ----
    if (bid == 0) {
        int p = tid;
        g_x[p] = xin[p];
        g_tok_used[p] = -1;
        g_conf[p] = NEGF;
        g_x0[p] = 0;
        if (p < NR) g_row_tok[p] = -1;
        __syncthreads();
        if (g_x[p] == MASK_ID) {
            int s = p & (SS - 1);
            int t = g_x[(s == 0) ? p : p - 1];
            for (int r = 0; r < NR; r++) {
                int old = atomicCAS(&g_row_tok[r], -1, t);
                if (old == -1 || old == t) break;
            }
        }
    }
    grid.sync();

    for (int step = 0; step < NSTEPS; step++) {
        // stage row tokens / count per block
        if (tid == 0) {
            int n = 0;
            while (n < NR && g_row_tok[n] >= 0) n++;
            s_nact = n;
        }
        if (tid < NR) s_tok[tid] = g_row_tok[tid];
        __syncthreads();
        const int nact = s_nact;

        // ---- Phase H: h partials (blocks 0..63) | hist zero (64..255) ----
        if (bid < NDC_H) {
            if (nact > 0) {
                int dbase = bid * 16;
                if (tid < nact * 16) {
                    int r = tid >> 4, dd = tid & 15;
                    se[r][dd] = emb[(size_t)s_tok[r] * DIM + dbase + dd];
                }
                __syncthreads();
                float w[16];
                #pragma unroll
                for (int dd = 0; dd < 16; dd++)
                    w[dd] = W1[(size_t)(dbase + dd) * DIM + tid];
                for (int r = 0; r < nact; r++) {
                    float a = 0.f;
                    #pragma unroll
                    for (int dd = 0; dd < 16; dd++) a += se[r][dd] * w[dd];
                    g_h_part[bid][r][tid] = a;
                }
            }
        } else {
            int idx = (bid - NDC_H) * 1024 + tid;    // < 196608
            if (idx < NR * 16384) {
                int r = idx >> 14, j = idx & 16383;
                if (r < nact)
                    ((uint4*)g_hist16[r])[j] = make_uint4(0u, 0u, 0u, 0u);
            }
        }
        grid.sync();

        // ---- Phase Hc: combine + tanh (blocks 0..nact-1) ----
        if (bid < nact) {
            float s = 0.f;
            #pragma unroll 8
            for (int p = 0; p < NDC_H; p++) s += g_h_part[p][bid][tid];
            g_h[bid][tid] = tanhf(s);
        }
        grid.sync();

        // ---- Phase L: logits partials (all 256 blocks) ----
        {
            int dc = bid & 31, cb = bid >> 5;
            if (tid < NR * 32) {
                int r = tid >> 5, dd = tid & 31;
                sh[r][dd] = (r < nact) ? g_h[r][dc * 32 + dd] : 0.f;
            }
            __syncthreads();
            int c = cb * 4096 + tid * 4;
            if (nact > 0 && c < VOCAB) {
                switch (nact) {
                    case 1: accumL<1>(Wout, sh, dc, c); break;
                    case 2: accumL<2>(Wout, sh, dc, c); break;
                    case 3: accumL<3>(Wout, sh, dc, c); break;
                    case 4: accumL<4>(Wout, sh, dc, c); break;
                    default: accumL<NR>(Wout, sh, dc, c); break;
                }
            }
            __syncthreads();
        }
        grid.sync();

        // ---- Phase C: combine + penalty + hist + wave chunk-stats ----
        {
            int wid = bid * 16 + (tid >> 6);
            int lane = tid & 63;
            if (wid < nact * NCH) {
                int r = wid / NCH, chunk = wid % NCH;
                int c = chunk * 64 + lane;
                float v = 0.f;
                #pragma unroll 8
                for (int dc = 0; dc < NDCL; dc++) v += g_lpart[dc][r][c];
                if (c == EXPAND_ID) v -= 1e9f;
                g_logits[r][c] = v;
                atomicAdd(&g_hist16[r][keyf(v) >> 16], 1u);
                float bv = v; int bi = c;
                #pragma unroll
                for (int off = 1; off < 64; off <<= 1) {
                    float ov = __shfl_xor(bv, off, 64);
                    int   oi = __shfl_xor(bi, off, 64);
                    if (ov > bv || (ov == bv && oi < bi)) { bv = ov; bi = oi; }
                }
                float z = expf(v - bv);
                #pragma unroll
                for (int off = 1; off < 64; off <<= 1)
                    z += __shfl_xor(z, off, 64);
                if (lane == 0) {
                    g_cmax[r][chunk]  = bv;
                    g_camax[r][chunk] = bi;
                    g_cz[r][chunk]    = z;
                }
            }
        }
        grid.sync();

        // ---- Phase F1 (blocks 0..nact-1): row max/argmax/Z ----
        //      Phase F2 (blocks 8..8+nact-1): hist threshold scan ----
        if (bid < nact) {
            int r = bid;
            float bv = NEGF; int bi = 0x7fffffff;
            if (tid < NCH) { bv = g_cmax[r][tid]; bi = g_camax[r][tid]; }
            red_f[tid] = bv; red_i[tid] = bi;
            __syncthreads();
            for (int o = 512; o; o >>= 1) {
                if (tid < o) {
                    if (red_f[tid + o] > red_f[tid] ||
                        (red_f[tid + o] == red_f[tid] && red_i[tid + o] < red_i[tid])) {
                        red_f[tid] = red_f[tid + o]; red_i[tid] = red_i[tid + o];
                    }
                }
                __syncthreads();
            }
            float mx = red_f[0];
            int   am = red_i[0];
            if (tid == 0) { g_mx_r[r] = mx; g_amax_r[r] = am; }
            __syncthreads();
            float z = 0.f;
            if (tid < NCH) z = g_cz[r][tid] * expf(g_cmax[r][tid] - mx);
            red_f[tid] = z;
            __syncthreads();
            for (int o = 512; o; o >>= 1) {
                if (tid < o) red_f[tid] += red_f[tid + o];
                __syncthreads();
            }
            if (tid == 0) g_Z_r[r] = red_f[0];
        } else if (bid >= NR && bid < NR + nact) {
            int r = bid - NR;
            const uint4* H4 = (const uint4*)&g_hist16[r][tid * 64];
            unsigned loc = 0;
            #pragma unroll
            for (int i = 0; i < 16; i++) {
                uint4 h = H4[i];
                loc += h.x + h.y + h.z + h.w;
            }
            su_[tid] = loc;
            __syncthreads();
            if (tid < 32) {
                unsigned s2 = 0;
                for (int j = 0; j < 32; j++) s2 += su_[tid * 32 + j];
                sup[tid] = s2;
            }
            __syncthreads();
            if (tid == 0) {
                unsigned cum = 0; int w = 31;
                for (; w > 0; w--) { if (cum + sup[w] >= TOPK) break; cum += sup[w]; }
                int j = w * 32 + 31;
                for (; j > w * 32; j--) { if (cum + su_[j] >= TOPK) break; cum += su_[j]; }
                const unsigned* H = g_hist16[r];
                int T = j * 64;
                for (int b = j * 64 + 63; b >= j * 64; b--) {
                    unsigned cc = H[b];
                    if (cum + cc >= TOPK) { T = b; break; }
                    cum += cc;
                }
                g_thr[r] = (unsigned)T;
                g_cand_cnt[r] = 0;
            }
        }
        grid.sync();

        // ---- Phase F3: gather candidates (all blocks) ----
        {
            int i = bid * 1024 + tid;
            if (i < nact * VOCAB) {
                int r = i / VOCAB, c = i % VOCAB;
                float v = g_logits[r][c];
                if ((keyf(v) >> 16) >= g_thr[r]) {
                    int j = atomicAdd(&g_cand_cnt[r], 1);
                    if (j < CAP) g_cand[r][j] = v;
                }
            }
        }
        grid.sync();

        // ---- Phase F4 (block 0): sort+conf, scatter, argmax, reveal, requests
        if (bid == 0) {
            int r = tid >> 7, lane = tid & 127;
            bool act = (r < nact);
            int n = 0;
            if (act) {
                n = g_cand_cnt[r]; if (n > CAP) n = CAP;
                for (int i = lane; i < n; i += 128) candL[r][i] = g_cand[r][i];
            }
            __syncthreads();
            if (act) {
                for (int i = lane; i < n; i += 128) {
                    unsigned ki = keyf(candL[r][i]);
                    int rank = 0;
                    for (int j = 0; j < n; j++) {
                        unsigned kj = keyf(candL[r][j]);
                        rank += (kj > ki) || (kj == ki && j < i);
                    }
                    if (rank < TOPK) sorted_[r][rank] = candL[r][i];
                }
            }
            __syncthreads();
            if (act && lane == 0) {
                int m = n; if (m > TOPK) m = TOPK;
                float mx  = g_mx_r[r];
                float run = expf(sorted_[r][0] - mx);    // == 1
                float lim = 0.9f * g_Z_r[r];
                for (int j = 1; j < m; j++) {
                    if (run > lim) break;                // top-p boundary
                    run += expf(sorted_[r][j] - mx);
                }
                g_row_conf[r] = 1.0f / run;
                g_row_x0[r]   = g_amax_r[r];
            }
            __syncthreads();
            // scatter + global argmax + reveal
            int p = tid;
            float myconf;
            if (g_x[p] != MASK_ID) {
                myconf = NEGF; g_conf[p] = NEGF;
            } else {
                myconf = g_conf[p];
                int s = p & (SS - 1);
                int t = g_x[(s == 0) ? p : p - 1];
                for (int rr = 0; rr < NR; rr++) {
                    if (g_row_tok[rr] == t) {
                        myconf = g_row_conf[rr];
                        g_conf[p] = myconf;
                        g_x0[p]   = g_row_x0[rr];
                        g_tok_used[p] = t;
                        break;
                    }
                }
            }
            red_f[p] = myconf; red_i[p] = p;
            __syncthreads();
            for (int o = 512; o; o >>= 1) {
                if (p < o) {
                    if (red_f[p + o] > red_f[p] ||
                        (red_f[p + o] == red_f[p] && red_i[p + o] < red_i[p])) {
                        red_f[p] = red_f[p + o]; red_i[p] = red_i[p + o];
                    }
                }
                __syncthreads();
            }
            if (p == 0) {
                float cc = red_f[0]; int idx = red_i[0];
                g_step_conf[step] = cc;
                if (cc > 0.f) g_x[idx] = g_x0[idx];   // any-mask guard
            }
            __syncthreads();
            // next-step requests
            if (p < NR) g_row_tok[p] = -1;
            __syncthreads();
            if (g_x[p] == MASK_ID) {
                int s2 = p & (SS - 1);
                int t2 = g_x[(s2 == 0) ? p : p - 1];
                if (t2 != g_tok_used[p]) {
                    for (int rr = 0; rr < NR; rr++) {
                        int old = atomicCAS(&g_row_tok[rr], -1, t2);
                        if (old == -1 || old == t2) break;
                    }
                }
            }
        }
        grid.sync();
    }

    // ---- output ----
    if (bid == 0) {
        out[tid] = (float)g_x[tid];
        if (tid < NSTEPS) out[BS + tid] = g_step_conf[tid];
    }
}

extern "C" void kernel_launch(void* const* d_in, const int* in_sizes, int n_in,
                              void* d_out, int out_size, void* d_ws, size_t ws_size,
                              hipStream_t stream) {
    const int*   x    = (const int*)  d_in[0];
    const float* emb  = (const float*)d_in[1];
    const float* W1   = (const float*)d_in[2];
    const float* Wout = (const float*)d_in[3];
    float*       out  = (float*)d_out;

    void* args[] = { (void*)&x, (void*)&emb, (void*)&W1, (void*)&Wout, (void*)&out };
    hipLaunchCooperativeKernel((void*)k_mega, dim3(256), dim3(1024), args, 0, stream);
}

// Round 7
// 351.406 us; speedup vs baseline: 3.1267x; 3.1267x over previous
//
#include <hip/hip_runtime.h>
#include <hip/hip_bf16.h>
#include <math.h>

#define VOCAB 32000
#define DIM 1024
#define BB 2
#define SS 512
#define BS (BB*SS)
#define MASK_ID 31999
#define EXPAND_ID 31998
#define NSTEPS 4
#define TOPK 50
#define NR 8
#define NEGF (-3.4028234663852886e38f)

#define NBLK_A 32         // h kernel blocks
#define NBLK_B 250        // logits blocks: 128 cols each
#define CAP 256           // candidate capacity

// -------- persistent device state (re-initialized every kernel_launch) ------
__device__ int      g_x[BS];
__device__ int      g_x0[BS];
__device__ int      g_tok_used[BS];
__device__ float    g_conf[BS];
__device__ int      g_row_tok[NR];     // CAS-compacted: active rows 0..nact-1
__device__ float    g_row_conf[NR];
__device__ int      g_row_x0[NR];
__device__ float    g_h[NR][DIM];
__device__ float    g_logits[NR][VOCAB];
__device__ float    g_step_conf[NSTEPS];
__device__ unsigned g_hist16[NR][65536];
__device__ float    g_cmax[NR][NBLK_B];
__device__ int      g_camax[NR][NBLK_B];
__device__ float    g_cz[NR][NBLK_B];
__device__ int      g_cand_cnt[NR];
__device__ float    g_cand[NR][CAP];

__device__ inline unsigned keyf(float f) {
    unsigned b = __float_as_uint(f);
    return b ^ ((b & 0x80000000u) ? 0xFFFFFFFFu : 0x80000000u);
}

// 1 block, 1024 threads: init all state + step-0 requests (BS == 1024)
__global__ __launch_bounds__(1024) void k_start(const int* __restrict__ x) {
    int p = threadIdx.x;
    g_x[p] = x[p];
    g_tok_used[p] = -1;
    g_conf[p] = NEGF;
    g_x0[p] = 0;
    if (p < NR) g_row_tok[p] = -1;
    __syncthreads();
    if (g_x[p] != MASK_ID) return;
    int s = p & (SS - 1);
    int t = g_x[(s == 0) ? p : p - 1];
    for (int r = 0; r < NR; r++) {
        int old = atomicCAS(&g_row_tok[r], -1, t);
        if (old == -1 || old == t) return;
    }
}

// h = tanh(emb[tok] @ W1), full-K, + fused hist zero.
// grid NBLK_A=32, block 1024 = 32 cols x 32 K-groups (32 d each).
__global__ __launch_bounds__(1024) void k_h(const float* __restrict__ emb,
                                            const float* __restrict__ W1) {
    __shared__ int   s_tok[NR];
    __shared__ int   s_nact;
    __shared__ float se[NR][DIM];      // 32 KB
    __shared__ float red[32][33];      // padded
    int tid = threadIdx.x, bid = blockIdx.x;
    if (tid == 0) {
        int n = 0;
        while (n < NR && g_row_tok[n] >= 0) n++;
        s_nact = n;
    }
    if (tid < NR) s_tok[tid] = g_row_tok[tid];
    __syncthreads();
    const int nact = s_nact;
    // fused: zero hist16 for active rows (16384 uint4 per row)
    for (int idx = bid * 1024 + tid; idx < nact * 16384; idx += NBLK_A * 1024) {
        int r = idx >> 14, j = idx & 16383;
        ((uint4*)g_hist16[r])[j] = make_uint4(0u, 0u, 0u, 0u);
    }
    if (nact == 0) return;
    for (int i = tid; i < nact * DIM; i += 1024) {
        int r = i >> 10, d = i & (DIM - 1);
        se[r][d] = emb[(size_t)s_tok[r] * DIM + d];
    }
    __syncthreads();
    const int ct = tid & 31, kg = tid >> 5;
    const int col = bid * 32 + ct;
    float acc[NR];
    #pragma unroll
    for (int r = 0; r < NR; r++) acc[r] = 0.f;
    #pragma unroll 4
    for (int dd = 0; dd < 32; dd++) {
        int d = kg * 32 + dd;
        float w = W1[(size_t)d * DIM + col];
        #pragma unroll
        for (int r = 0; r < NR; r++)
            if (r < nact) acc[r] += se[r][d] * w;
    }
    for (int r = 0; r < nact; r++) {           // nact is block-uniform
        red[kg][ct] = acc[r];
        __syncthreads();
        for (int o = 16; o; o >>= 1) {
            if (kg < o) red[kg][ct] += red[kg + o][ct];
            __syncthreads();
        }
        if (kg == 0) g_h[r][col] = tanhf(red[0][ct]);
        __syncthreads();
    }
}

// per-row-count-specialized logits + block stats body
template<int NA>
__device__ __forceinline__ void blog(const float* __restrict__ Wout,
                                     const float (*hh)[DIM],
                                     float4 (*red)[32],
                                     int cbase, int ct, int kg, int bid) {
    float4 acc[NA];
    #pragma unroll
    for (int r = 0; r < NA; r++) acc[r] = make_float4(0.f, 0.f, 0.f, 0.f);
    const float* Wp = Wout + (size_t)(kg * 32) * VOCAB + cbase + ct * 4;
    #pragma unroll 4
    for (int dd = 0; dd < 32; dd++) {
        float4 w = *(const float4*)(Wp + (size_t)dd * VOCAB);
        #pragma unroll
        for (int r = 0; r < NA; r++) {
            float s = hh[r][kg * 32 + dd];
            acc[r].x += s * w.x; acc[r].y += s * w.y;
            acc[r].z += s * w.z; acc[r].w += s * w.w;
        }
    }
    for (int r = 0; r < NA; r++) {
        red[kg][ct] = acc[r];
        __syncthreads();
        for (int o = 16; o; o >>= 1) {
            if (kg < o) {
                float4 a = red[kg][ct], b = red[kg + o][ct];
                a.x += b.x; a.y += b.y; a.z += b.z; a.w += b.w;
                red[kg][ct] = a;
            }
            __syncthreads();
        }
        if (kg == 0) {
            float4 f = red[0][ct];
            float vv[4] = {f.x, f.y, f.z, f.w};
            int c0 = cbase + ct * 4;
            #pragma unroll
            for (int q = 0; q < 4; q++)
                if (c0 + q == EXPAND_ID) vv[q] -= 1e9f;
            *(float4*)&g_logits[r][c0] = make_float4(vv[0], vv[1], vv[2], vv[3]);
            #pragma unroll
            for (int q = 0; q < 4; q++)
                atomicAdd(&g_hist16[r][keyf(vv[q]) >> 16], 1u);
            // chunk max + first-index argmax over this block's 128 cols
            float bv = vv[0]; int bi = c0;
            #pragma unroll
            for (int q = 1; q < 4; q++)
                if (vv[q] > bv) { bv = vv[q]; bi = c0 + q; }
            #pragma unroll
            for (int off = 1; off < 32; off <<= 1) {
                float ov = __shfl_xor(bv, off, 32);
                int   oi = __shfl_xor(bi, off, 32);
                if (ov > bv || (ov == bv && oi < bi)) { bv = ov; bi = oi; }
            }
            float z = 0.f;
            #pragma unroll
            for (int q = 0; q < 4; q++) z += expf(vv[q] - bv);
            #pragma unroll
            for (int off = 1; off < 32; off <<= 1)
                z += __shfl_xor(z, off, 32);
            if (ct == 0) {
                g_cmax[r][bid]  = bv;
                g_camax[r][bid] = bi;
                g_cz[r][bid]    = z;
            }
        }
        __syncthreads();
    }
}

// logits + chunk stats, full-K: grid NBLK_B=250, block 1024
// threads = 32 float4-col-threads x 32 K-groups (32 d each)
__global__ __launch_bounds__(1024) void k_logits_stats(const float* __restrict__ Wout) {
    __shared__ float  hh[NR][DIM];     // 32 KB
    __shared__ float4 red[32][32];     // 16 KB
    __shared__ int    s_nact;
    int tid = threadIdx.x, bid = blockIdx.x;
    if (tid == 0) {
        int n = 0;
        while (n < NR && g_row_tok[n] >= 0) n++;
        s_nact = n;
    }
    __syncthreads();
    const int nact = s_nact;
    if (nact == 0) return;
    for (int i = tid; i < nact * DIM; i += 1024) {
        int r = i >> 10, d = i & (DIM - 1);
        hh[r][d] = g_h[r][d];
    }
    __syncthreads();
    const int ct = tid & 31, kg = tid >> 5;
    const int cbase = bid * 128;
    switch (nact) {
        case 1: blog<1>(Wout, hh, red, cbase, ct, kg, bid); break;
        case 2: blog<2>(Wout, hh, red, cbase, ct, kg, bid); break;
        case 3: blog<3>(Wout, hh, red, cbase, ct, kg, bid); break;
        case 4: blog<4>(Wout, hh, red, cbase, ct, kg, bid); break;
        default: blog<NR>(Wout, hh, red, cbase, ct, kg, bid); break;
    }
}

// 1 block, 1024 threads: chunk-reduce, hist scan, gather, sort+conf,
// scatter, global argmax, reveal, next-step requests, (last step: output)
__global__ __launch_bounds__(1024) void k_finish(int step, float* __restrict__ out) {
    __shared__ float    red_f[1024];
    __shared__ int      red_i[1024];
    __shared__ unsigned su_[1024];
    __shared__ unsigned sup[32];
    __shared__ float    candL[NR][CAP];    // 8 KB
    __shared__ int      cand_n[NR];
    __shared__ float    sorted_[NR][TOPK];
    __shared__ float    s_mx[NR];
    __shared__ int      s_am[NR];
    __shared__ float    s_Zr[NR];
    __shared__ unsigned s_thr[NR];
    __shared__ int      s_nact;

    int tid = threadIdx.x;
    if (tid == 0) {
        int n = 0;
        while (n < NR && g_row_tok[n] >= 0) n++;
        s_nact = n;
    }
    if (tid < NR) cand_n[tid] = 0;
    __syncthreads();
    const int nact = s_nact;
    int r = tid >> 7, lane = tid & 127;
    bool act = (r < nact);

    // --- Phase A: per-row chunk reduce (128-lane group per row, 250 chunks) ---
    float bv = NEGF; int bi = 0x7fffffff;
    if (act) {
        bv = g_cmax[r][lane]; bi = g_camax[r][lane];
        if (lane + 128 < NBLK_B) {
            float v2 = g_cmax[r][lane + 128]; int i2 = g_camax[r][lane + 128];
            if (v2 > bv || (v2 == bv && i2 < bi)) { bv = v2; bi = i2; }
        }
    }
    red_f[tid] = bv; red_i[tid] = bi;
    __syncthreads();
    for (int o = 64; o; o >>= 1) {
        if (lane < o) {
            if (red_f[tid + o] > red_f[tid] ||
                (red_f[tid + o] == red_f[tid] && red_i[tid + o] < red_i[tid])) {
                red_f[tid] = red_f[tid + o]; red_i[tid] = red_i[tid + o];
            }
        }
        __syncthreads();
    }
    if (act && lane == 0) { s_mx[r] = red_f[tid]; s_am[r] = red_i[tid]; }
    __syncthreads();
    float z = 0.f;
    if (act) {
        float mx = s_mx[r];
        z = g_cz[r][lane] * expf(g_cmax[r][lane] - mx);
        if (lane + 128 < NBLK_B)
            z += g_cz[r][lane + 128] * expf(g_cmax[r][lane + 128] - mx);
    }
    red_f[tid] = z;
    __syncthreads();
    for (int o = 64; o; o >>= 1) {
        if (lane < o) red_f[tid] += red_f[tid + o];
        __syncthreads();
    }
    if (act && lane == 0) s_Zr[r] = red_f[tid];
    __syncthreads();

    // --- Phase B: hist threshold-bin scan (rows serial, all threads) ---
    for (int rr = 0; rr < nact; rr++) {
        const uint4* H4 = (const uint4*)&g_hist16[rr][tid * 64];
        unsigned loc = 0;
        #pragma unroll
        for (int i = 0; i < 16; i++) {
            uint4 h = H4[i];
            loc += h.x + h.y + h.z + h.w;
        }
        su_[tid] = loc;
        __syncthreads();
        if (tid < 32) {
            unsigned s2 = 0;
            for (int j = 0; j < 32; j++) s2 += su_[tid * 32 + j];
            sup[tid] = s2;
        }
        __syncthreads();
        if (tid == 0) {
            unsigned cum = 0; int w = 31;
            for (; w > 0; w--) { if (cum + sup[w] >= TOPK) break; cum += sup[w]; }
            int j = w * 32 + 31;
            for (; j > w * 32; j--) { if (cum + su_[j] >= TOPK) break; cum += su_[j]; }
            const unsigned* H = g_hist16[rr];
            int T = j * 64;
            for (int b = j * 64 + 63; b >= j * 64; b--) {
                unsigned cc = H[b];
                if (cum + cc >= TOPK) { T = b; break; }
                cum += cc;
            }
            s_thr[rr] = (unsigned)T;
        }
        __syncthreads();
    }

    // --- Phase C: gather candidates >= threshold bin (rows serial) ---
    for (int rr = 0; rr < nact; rr++) {
        unsigned T = s_thr[rr];
        const float4* L4 = (const float4*)g_logits[rr];
        #pragma unroll
        for (int i = 0; i < 8; i++) {
            int idx = i * 1024 + tid;
            if (idx < VOCAB / 4) {
                float4 v4 = L4[idx];
                float vv[4] = {v4.x, v4.y, v4.z, v4.w};
                #pragma unroll
                for (int q = 0; q < 4; q++) {
                    if ((keyf(vv[q]) >> 16) >= T) {
                        int j = atomicAdd(&cand_n[rr], 1);
                        if (j < CAP) candL[rr][j] = vv[q];
                    }
                }
            }
        }
    }
    __syncthreads();

    // --- Phase D: rank-sort top-50 + conf (128-lane group per row) ---
    if (act) {
        int n = cand_n[r]; if (n > CAP) n = CAP;
        for (int i = lane; i < n; i += 128) {
            unsigned ki = keyf(candL[r][i]);
            int rank = 0;
            for (int j = 0; j < n; j++) {
                unsigned kj = keyf(candL[r][j]);
                rank += (kj > ki) || (kj == ki && j < i);
            }
            if (rank < TOPK) sorted_[r][rank] = candL[r][i];
        }
    }
    __syncthreads();
    if (act && lane == 0) {
        int n = cand_n[r]; if (n > CAP) n = CAP;
        int m = n; if (m > TOPK) m = TOPK;
        float mx  = s_mx[r];
        float run = expf(sorted_[r][0] - mx);    // == 1
        float lim = 0.9f * s_Zr[r];
        for (int j = 1; j < m; j++) {
            if (run > lim) break;                // top-p removal boundary
            run += expf(sorted_[r][j] - mx);
        }
        g_row_conf[r] = 1.0f / run;
        g_row_x0[r]   = s_am[r];
    }
    __syncthreads();

    // --- Phase E: scatter + global argmax + reveal + next requests ---
    int p = tid;
    float myconf;
    if (g_x[p] != MASK_ID) {
        myconf = NEGF; g_conf[p] = NEGF;
    } else {
        myconf = g_conf[p];                      // cached from earlier steps
        int s = p & (SS - 1);
        int t = g_x[(s == 0) ? p : p - 1];
        #pragma unroll
        for (int rr = 0; rr < NR; rr++) {
            if (g_row_tok[rr] == t) {
                myconf = g_row_conf[rr];
                g_conf[p] = myconf;
                g_x0[p]   = g_row_x0[rr];
                g_tok_used[p] = t;
                break;
            }
        }
    }
    red_f[p] = myconf; red_i[p] = p;
    __syncthreads();
    for (int o = 512; o; o >>= 1) {
        if (p < o) {
            if (red_f[p + o] > red_f[p] ||
                (red_f[p + o] == red_f[p] && red_i[p + o] < red_i[p])) {
                red_f[p] = red_f[p + o]; red_i[p] = red_i[p + o];
            }
        }
        __syncthreads();
    }
    if (p == 0) {
        float c = red_f[0]; int idx = red_i[0];
        g_step_conf[step] = c;
        if (c > 0.f) g_x[idx] = g_x0[idx];       // any-mask guard: conf > 0
    }
    __syncthreads();
    if (step == NSTEPS - 1) {
        // final output
        out[p] = (float)g_x[p];
        if (p < NSTEPS) out[BS + p] = g_step_conf[p];
        return;
    }
    // next-step requests (post-reveal)
    if (p < NR) g_row_tok[p] = -1;
    __syncthreads();
    if (g_x[p] != MASK_ID) return;
    int s2 = p & (SS - 1);
    int t2 = g_x[(s2 == 0) ? p : p - 1];
    if (t2 == g_tok_used[p]) return;
    for (int rr = 0; rr < NR; rr++) {
        int old = atomicCAS(&g_row_tok[rr], -1, t2);
        if (old == -1 || old == t2) return;
    }
}

extern "C" void kernel_launch(void* const* d_in, const int* in_sizes, int n_in,
                              void* d_out, int out_size, void* d_ws, size_t ws_size,
                              hipStream_t stream) {
    const int*   x    = (const int*)  d_in[0];
    const float* emb  = (const float*)d_in[1];
    const float* W1   = (const float*)d_in[2];
    const float* Wout = (const float*)d_in[3];
    float*       out  = (float*)d_out;

    k_start<<<1, 1024, 0, stream>>>(x);
    for (int s = 0; s < NSTEPS; s++) {
        k_h<<<NBLK_A, 1024, 0, stream>>>(emb, W1);
        k_logits_stats<<<NBLK_B, 1024, 0, stream>>>(Wout);
        k_finish<<<1, 1024, 0, stream>>>(s, out);
    }
}